// Round 2
// baseline (713.381 us; speedup 1.0000x reference)
//
#include <hip/hip_runtime.h>
#include <hip/hip_bf16.h>

// ---------------- problem constants ----------------
#define NTOK 768
#define DT   447
#define CS   384
#define TFD  831          // 447+384
#define TFDP 832          // padded K for MFMA (26*32)
#define CZ   128
#define RELD 139
#define NCOL 640          // 384 (s_init) + 128 (a) + 128 (b)

// d_out offsets (in floats)
#define OFF_SINIT  (NTOK*TFD)                    // 638208
#define OFF_Z      (OFF_SINIT + NTOK*CS)         // 933120
#define OFF_REL    (OFF_Z + NTOK*NTOK*CZ)        // 76430592

// ws byte offsets (all 16B aligned)
#define WSB_A    0                // 768*128 f32   = 393216 B
#define WSB_B    393216           // 768*128 f32
#define WSB_WPT  786432           // 139*128 bf16  = 35584 B
#define WSB_SB   822016           // 768*832 bf16  = 1277952 B
#define WSB_WB   2099968          // 640*832 bf16  = 1064960 B

using short8 = __attribute__((ext_vector_type(8))) short;
using f32x4  = __attribute__((ext_vector_type(4))) float;

__device__ __forceinline__ unsigned short f2bf(float v) {
    __hip_bfloat16 h = __float2bfloat16(v);
    return *reinterpret_cast<unsigned short*>(&h);
}
__device__ __forceinline__ float4 bf16x4_to_f32(unsigned long long g) {
    unsigned lo = (unsigned)g, hi = (unsigned)(g >> 32);
    float4 r;
    r.x = __uint_as_float(lo << 16);
    r.y = __uint_as_float(lo & 0xffff0000u);
    r.z = __uint_as_float(hi << 16);
    r.w = __uint_as_float(hi & 0xffff0000u);
    return r;
}

// pack = rd | ((66+td)<<8) | ((133+cd)<<16) | (se<<24)  -- row indices pre-biased into wt table space
__device__ __forceinline__ int make_pack(int ti, int ri, int ai, int ei, int si,
                                         int tj, int rj, int aj, int ej, int sj) {
    int sc = (ai == aj);
    int sr = (ri == rj);
    int se = (ei == ej);
    int rdist = min(max(ri - rj + 32, 0), 64); int rd = sc ? rdist : 65;
    int tdist = min(max(ti - tj + 32, 0), 64); int td = (sc && sr) ? tdist : 65;
    int cdist = min(max(si - sj + 2, 0), 4);   int cd = se ? cdist : 5;
    return rd | ((66 + td) << 8) | ((133 + cd) << 16) | (se << 24);
}

// ---------------- kernel 1: concat + bf16 copies + W_pos transpose ----------------
#define PREP_TOTAL 1189248
__launch_bounds__(256)
__global__ void prep_kernel(const float* __restrict__ tf, const float* __restrict__ ta,
                            const float* __restrict__ Wsingle, const float* __restrict__ Wleft,
                            const float* __restrict__ Wright, const float* __restrict__ wpos,
                            float* __restrict__ s_input, short* __restrict__ Sb,
                            short* __restrict__ Wb, unsigned short* __restrict__ wpt) {
    int idx = blockIdx.x * 256 + threadIdx.x;
    if (idx < NTOK * TFD) {
        int n = idx / TFD;
        int d = idx - n * TFD;
        float v = (d < DT) ? tf[n * DT + d] : ta[n * CS + (d - DT)];
        s_input[idx] = v;
        Sb[n * TFDP + d] = (short)f2bf(v);
    } else if (idx < NTOK * TFD + NTOK) {
        int n = idx - NTOK * TFD;
        Sb[n * TFDP + TFD] = 0;            // K pad
    } else if (idx < NTOK * TFD + NTOK + NCOL * TFDP) {
        int t = idx - (NTOK * TFD + NTOK);
        int c = t / TFDP;
        int d = t - c * TFDP;
        float v;
        if (d >= TFD)       v = 0.f;       // K pad
        else if (c < 384)   v = Wsingle[c * TFD + d];
        else if (c < 512)   v = Wleft[(c - 384) * TFD + d];
        else                v = Wright[(c - 512) * TFD + d];
        Wb[t] = (short)f2bf(v);
    } else {
        int t = idx - (NTOK * TFD + NTOK + NCOL * TFDP);
        if (t < RELD * CZ) {
            int r = t >> 7;                 // / 128
            int c = t & 127;
            wpt[t] = f2bf(wpos[c * RELD + r]);   // transpose to (r, c)
        }
    }
}

// ---------------- kernel 2: bf16 MFMA GEMM (one 16x16 tile per wave) ----------------
__launch_bounds__(256)
__global__ void mfma_gemm_kernel(const short* __restrict__ Sb, const short* __restrict__ Wb,
                                 float* __restrict__ s_init, float* __restrict__ a_out,
                                 float* __restrict__ b_out) {
    int tid  = threadIdx.x;
    int lane = tid & 63;
    int wv   = tid >> 6;
    int m0 = blockIdx.x * 16;              // 0..47 tiles
    int n0 = (blockIdx.y * 4 + wv) * 16;   // 0..39 tiles
    int fr   = lane & 15;
    int koff = (lane >> 4) * 8;

    const short* ap = Sb + (m0 + fr) * TFDP + koff;
    const short* bp = Wb + (n0 + fr) * TFDP + koff;
    f32x4 acc = {0.f, 0.f, 0.f, 0.f};
    #pragma unroll 4
    for (int k = 0; k < TFDP; k += 32) {
        short8 af = *reinterpret_cast<const short8*>(ap + k);
        short8 bf = *reinterpret_cast<const short8*>(bp + k);
        acc = __builtin_amdgcn_mfma_f32_16x16x32_bf16(af, bf, acc, 0, 0, 0);
    }
    float* dst; int ldc, c0;
    if (n0 < 384)      { dst = s_init; ldc = 384; c0 = n0; }
    else if (n0 < 512) { dst = a_out;  ldc = 128; c0 = n0 - 384; }
    else               { dst = b_out;  ldc = 128; c0 = n0 - 512; }
    int col = lane & 15;
    int r0  = (lane >> 4) * 4;             // C/D: col=lane&15, row=(lane>>4)*4+reg  [m89/m91]
    #pragma unroll
    for (int r = 0; r < 4; ++r)
        dst[(m0 + r0 + r) * ldc + c0 + col] = acc[r];
}

// ---------------- kernel 3: z_init writer (1 KB dwordx4 stores per wave-inst) ----------------
// grid = 768 (one block per i). Wave: lanes 0-31 -> row j, lanes 32-63 -> row j+1, float4/lane.
__launch_bounds__(256)
__global__ void z_writer(const float* __restrict__ a_in, const float* __restrict__ b_in,
                         const unsigned short* __restrict__ wpt_g,
                         const float* __restrict__ wbond, const float* __restrict__ contact,
                         const int* __restrict__ tok, const int* __restrict__ res,
                         const int* __restrict__ asym, const int* __restrict__ ent,
                         const int* __restrict__ sym, float* __restrict__ z_out) {
    __shared__ __align__(16) unsigned short wt[RELD * CZ];   // 35584 B
    __shared__ int   pks[NTOK];                              // 3072 B
    __shared__ float cfs[NTOK];                              // 3072 B -> 41728 B total, 3 blocks/CU
    int tid = threadIdx.x;
    int i   = blockIdx.x;

    for (int idx = tid; idx < (RELD * CZ) / 8; idx += 256)
        reinterpret_cast<uint4*>(wt)[idx] = reinterpret_cast<const uint4*>(wpt_g)[idx];

    int ti = tok[i], ri = res[i], ai = asym[i], ei = ent[i], si = sym[i];
    for (int j = tid; j < NTOK; j += 256) {
        pks[j] = make_pack(ti, ri, ai, ei, si, tok[j], res[j], asym[j], ent[j], sym[j]);
        cfs[j] = contact[i * NTOK + j];
    }

    int lane = tid & 63, wv = tid >> 6;
    int half = lane >> 5;
    int c0   = (lane & 31) * 4;
    float4 av  = *reinterpret_cast<const float4*>(&a_in[i * CZ + c0]);
    float4 wbv = *reinterpret_cast<const float4*>(&wbond[c0]);
    __syncthreads();

    unsigned long long uw = *reinterpret_cast<const unsigned long long*>(&wt[132 * CZ + c0]);
    float4 wse = bf16x4_to_f32(uw);
    size_t zbase = (size_t)i * NTOK * CZ;

    #pragma unroll 2
    for (int rr = 0; rr < 96; ++rr) {
        int j  = rr * 8 + wv * 2 + half;
        int pk = pks[j];
        float cf = cfs[j];
        float4 bv = *reinterpret_cast<const float4*>(&b_in[j * CZ + c0]);
        unsigned long long g0 = *reinterpret_cast<const unsigned long long*>(&wt[(pk & 255) * CZ + c0]);
        unsigned long long g1 = *reinterpret_cast<const unsigned long long*>(&wt[((pk >> 8) & 255) * CZ + c0]);
        unsigned long long g2 = *reinterpret_cast<const unsigned long long*>(&wt[((pk >> 16) & 255) * CZ + c0]);
        float pse = (float)((unsigned)pk >> 24);
        float4 f0 = bf16x4_to_f32(g0);
        float4 f1 = bf16x4_to_f32(g1);
        float4 f2 = bf16x4_to_f32(g2);
        float4 o;
        o.x = av.x + bv.x + f0.x + f1.x + f2.x + pse * wse.x + cf * wbv.x;
        o.y = av.y + bv.y + f0.y + f1.y + f2.y + pse * wse.y + cf * wbv.y;
        o.z = av.z + bv.z + f0.z + f1.z + f2.z + pse * wse.z + cf * wbv.z;
        o.w = av.w + bv.w + f0.w + f1.w + f2.w + pse * wse.w + cf * wbv.w;
        *reinterpret_cast<float4*>(&z_out[zbase + (size_t)j * CZ + c0]) = o;
    }
}

// ---------------- kernel 4: rel_feat writer (pure one-hot synthesis, dwordx4) ----------------
// grid = 768 (one block per i); thread t covers flat tile offsets [t*4, t*4+4) stride 1024.
__launch_bounds__(256)
__global__ void rel_writer(const int* __restrict__ tok, const int* __restrict__ res,
                           const int* __restrict__ asym, const int* __restrict__ ent,
                           const int* __restrict__ sym, float* __restrict__ rel_out) {
    __shared__ int pks[NTOK];
    int tid = threadIdx.x;
    int i   = blockIdx.x;
    int ti = tok[i], ri = res[i], ai = asym[i], ei = ent[i], si = sym[i];
    for (int j = tid; j < NTOK; j += 256)
        pks[j] = make_pack(ti, ri, ai, ei, si, tok[j], res[j], asym[j], ent[j], sym[j]);
    __syncthreads();

    const int tile = NTOK * RELD;                 // 106752 floats, 16B-aligned per i
    float* dst = rel_out + (size_t)i * tile;
    for (int f0 = tid * 4; f0 < tile; f0 += 1024) {
        unsigned jl = (unsigned)f0 / 139u;        // magic-mul div
        int r = f0 - (int)jl * RELD;
        float4 v;
        #pragma unroll
        for (int k = 0; k < 4; ++k) {
            int pk = pks[jl];
            int rd    = pk & 255;
            int td66  = (pk >> 8) & 255;
            int cd133 = (pk >> 16) & 255;
            float se  = (float)((unsigned)pk >> 24);
            float val = (r == rd || r == td66 || r == cd133) ? 1.f
                      : ((r == 132) ? se : 0.f);
            reinterpret_cast<float*>(&v)[k] = val;
            ++r;
            if (r == RELD) { r = 0; ++jl; }
        }
        *reinterpret_cast<float4*>(&dst[f0]) = v;
    }
}

// ---------------- launcher ----------------
extern "C" void kernel_launch(void* const* d_in, const int* in_sizes, int n_in,
                              void* d_out, int out_size, void* d_ws, size_t ws_size,
                              hipStream_t stream) {
    const float* tf      = (const float*)d_in[0];
    const float* ta      = (const float*)d_in[1];
    const float* contact = (const float*)d_in[2];
    const int*   tok     = (const int*)d_in[3];
    const int*   res     = (const int*)d_in[4];
    const int*   asym    = (const int*)d_in[5];
    const int*   ent     = (const int*)d_in[6];
    const int*   sym     = (const int*)d_in[7];
    const float* Wsingle = (const float*)d_in[8];
    const float* Wleft   = (const float*)d_in[9];
    const float* Wright  = (const float*)d_in[10];
    const float* Wpos    = (const float*)d_in[11];
    const float* Wbond   = (const float*)d_in[12];

    float* out     = (float*)d_out;
    float* s_input = out;
    float* s_init  = out + OFF_SINIT;
    float* z       = out + OFF_Z;
    float* rel     = out + OFF_REL;

    char* wsb = (char*)d_ws;
    float*          a_ws = (float*)(wsb + WSB_A);
    float*          b_ws = (float*)(wsb + WSB_B);
    unsigned short* wpt  = (unsigned short*)(wsb + WSB_WPT);
    short*          Sb   = (short*)(wsb + WSB_SB);
    short*          Wb   = (short*)(wsb + WSB_WB);

    prep_kernel<<<(PREP_TOTAL + 255) / 256, 256, 0, stream>>>(
        tf, ta, Wsingle, Wleft, Wright, Wpos, s_input, Sb, Wb, wpt);

    mfma_gemm_kernel<<<dim3(48, 10), 256, 0, stream>>>(Sb, Wb, s_init, a_ws, b_ws);

    z_writer<<<768, 256, 0, stream>>>(
        a_ws, b_ws, wpt, Wbond, contact, tok, res, asym, ent, sym, z);

    rel_writer<<<768, 256, 0, stream>>>(tok, res, asym, ent, sym, rel);
}